// Round 4
// baseline (1264.709 us; speedup 1.0000x reference)
//
#include <hip/hip_runtime.h>
#include <stdint.h>

typedef unsigned int uint;
typedef unsigned short ushort;
typedef unsigned long long u64;

#define B_   8192
#define D_   128
#define N_   64
#define L_   3

typedef __attribute__((ext_vector_type(8))) short short8;
typedef __attribute__((ext_vector_type(4))) float f32x4;
union FragU { uint4 u; short8 h; };

__device__ __forceinline__ float bf2f(ushort u){ union{uint i; float f;} c; c.i=((uint)u)<<16; return c.f; }
__device__ __forceinline__ ushort f2bf(float f){ uint u=__float_as_uint(f); return (ushort)((u + 0x7fffu + ((u>>16)&1u))>>16); }
__device__ __forceinline__ uint pk2(float lo, float hi){ return (uint)f2bf(lo) | (((uint)f2bf(hi))<<16); }

// ---------------- LDS layout (bytes), 8 batches/block ----------------
#define OFF_X    0        // x residual f32 [8][132]  (stride 528)
#define XSTR     528
#define OFF_XH   4224     // bf16 A-operand [8][136] (stride 272)
#define XHSTR    272
#define OFF_QKA  6400     // qk_all bf16 [8 b][8 h][136] (b-stride 2176, h-stride 272)
#define OFF_H1   6400     // h1 bf16 [8][520] (stride 1040) — aliases QKA in FFN phase
#define OFF_QB   23808    // qb f32 [8][8]
#define OFF_MSK  24064    // u64 [8]
#define OFF_UA   24128    // U_all bf16 [8 b][1024+8pad] (stride 2064)
#define LDS_SZ   40640

struct P {
  const float *ego,*epos,*evel,*npos,*nvel;
  const int   *mask;
  const float *npW,*npb,*npg,*npbb;
  const float *ego_b,*ego_g,*ego_bb;
  const float *b2,*out_b,*out_g,*out_bb;
  const float *C0,*m2,*c2,*bo2,*b1F;
  const ushort *MT,*G,*W1B,*W2B,*egoT,*outT;
  ushort *nbg,*nbt; u64 *msk;
  float *outp;
};

// ================= prep kernels =================
// prep_bias: bq'(n1b fold), bk', bv' (nkv_b fold), b1'(n2b fold)
__global__ void prep_bias(const float* Wq,const float* bq,const float* n1b,
                          const float* Wk,const float* bk,const float* nkb,
                          const float* Wv,const float* bv,
                          const float* W1,const float* b1,const float* n2b,
                          float* bqp, float* bkp, float* bvp, float* b1F){
  int gid = blockIdx.x*256 + threadIdx.x;
  if (gid >= 3*896) return;
  int l = gid/896, c = gid%896;
  if (c < 384){
    int m = c>>7, j = c&127;
    const float* W = (m==0?Wq:(m==1?Wk:Wv)) + l*16384 + j;
    const float* nb = (m==0? n1b : nkb) + l*128;
    const float* bs = (m==0?bq:(m==1?bk:bv)) + l*128 + j;
    float a = *bs;
    for (int e=0;e<128;++e) a += nb[e]*W[e*128];
    float* dst = (m==0?bqp:(m==1?bkp:bvp));
    dst[l*128+j] = a;
  } else {
    int f = c-384;
    float a = b1[l*512+f];
    const float* W = W1 + l*65536 + f;
    const float* nb = n2b + l*128;
    for (int e=0;e<128;++e) a += nb[e]*W[e*512];
    b1F[l*512+f] = a;
  }
}

// prep_bias2: bo2[l][e] = bo[e] + sum_col bv'[col]*Wo[col][e]
__global__ void prep_bias2(const float* Wo, const float* bo, const float* bvp, float* bo2){
  int l = blockIdx.x, t = threadIdx.x;
  if (t < 128){
    float a = bo[l*128+t];
    const float* W = Wo + l*16384 + t;
    const float* bv = bvp + l*128;
    for (int c=0;c<128;++c) a += bv[c]*W[c*128];
    bo2[l*128+t] = a;
  }
}

// prep_MG: block=(l,h). MT[l][(h,d)][e], C0, m2, c2, G[l][e][(h,d)]
__global__ void prep_MG(const float* Wq,const float* Wk,const float* Wv,const float* Wo,
                        const float* n1g,const float* nkg,
                        const float* bqp,const float* bkp,
                        ushort* MT, float* C0, float* m2, float* c2, ushort* G){
  __shared__ float sWq[128][16], sWk[128][16], sWv[128][16], sWo[16][128];
  int l = blockIdx.x>>3, h = blockIdx.x&7, t = threadIdx.x;
  { int row = t>>1, hf = t&1;
    const float* q = Wq + l*16384 + row*128 + h*16 + hf*8;
    const float* k = Wk + l*16384 + row*128 + h*16 + hf*8;
    const float* v = Wv + l*16384 + row*128 + h*16 + hf*8;
    for (int j=0;j<8;++j){ sWq[row][hf*8+j]=q[j]; sWk[row][hf*8+j]=k[j]; sWv[row][hf*8+j]=v[j]; }
  }
  { int row = t>>4, sg = t&15;
    const float* o = Wo + l*16384 + (h*16+row)*128 + sg*8;
    for (int j=0;j<8;++j) sWo[row][sg*8+j]=o[j];
  }
  __syncthreads();
  // MT: thread e = t&127; loop d' (2 per iter, 64 iters)
  {
    int e = t&127;
    float g1 = 0.25f*n1g[l*128+e];
    float wq[16];
    #pragma unroll
    for (int j=0;j<16;++j) wq[j]=sWq[e][j];
    for (int k2=0;k2<64;++k2){
      int d = (t>>7) + 2*k2;
      float s=0.f;
      #pragma unroll
      for (int j=0;j<16;++j) s += wq[j]*sWk[d][j];
      MT[(size_t)l*131072 + (size_t)(h*128+d)*128 + e] = f2bf(g1*nkg[l*128+d]*s);
    }
    // m2
    if (t<128){
      float s=0.f;
      #pragma unroll
      for (int j=0;j<16;++j) s += wq[j]*bkp[l*128+h*16+j];
      m2[(l*128+e)*8+h] = g1*s;
    }
  }
  // C0: thread d' = t<128
  if (t<128){
    int d=t; float s=0.f;
    #pragma unroll
    for (int j=0;j<16;++j) s += bqp[l*128+h*16+j]*sWk[d][j];
    C0[l*1024 + h*128 + d] = 0.25f*nkg[l*128+d]*s;
  }
  if (t==0){
    float s=0.f;
    for (int j=0;j<16;++j) s += bqp[l*128+h*16+j]*bkp[l*128+h*16+j];
    c2[l*8+h] = 0.25f*s;
  }
  // G: thread d' = t&127; loop e
  {
    int d = t&127;
    float gk = nkg[l*128+d];
    float wv[16];
    #pragma unroll
    for (int j=0;j<16;++j) wv[j]=gk*sWv[d][j];
    for (int k2=0;k2<64;++k2){
      int e = (t>>7) + 2*k2;
      float s=0.f;
      #pragma unroll
      for (int j=0;j<16;++j) s += wv[j]*sWo[j][e];
      G[(size_t)l*131072 + (size_t)e*1024 + h*128 + d] = f2bf(s);
    }
  }
}

// prep_T: W1B[l][f][e]=n2g[e]*W1[e][f]; W2B[l][e][f]=W2[f][e]; egoT[c][e]; outT[c][e]
__global__ void prep_T(const float* W1,const float* n2g,const float* W2,
                       const float* egoW,const float* outW,
                       ushort* W1B, ushort* W2B, ushort* egoT, ushort* outT){
  int gid = blockIdx.x*256 + threadIdx.x;
  if (gid < 196608){
    int l = gid/65536, r = gid%65536, f = r>>7, e = r&127;
    W1B[gid] = f2bf(n2g[l*128+e]*W1[l*65536 + e*512 + f]);
  } else if (gid < 393216){
    int q = gid-196608; int l = q/65536, r = q%65536, e = r>>9, f = r&511;
    W2B[q] = f2bf(W2[l*65536 + f*128 + e]);
  } else if (gid < 409600){
    int q = gid-393216; int c = q>>7, e = q&127;
    egoT[q] = f2bf(egoW[e*128+c]);
  } else if (gid < 425984){
    int q = gid-409600; int c = q>>7, e = q&127;
    outT[q] = f2bf(outW[e*128+c]);
  }
}

// ================= st_nb: nbhat -> ws (n-major; MODE2 also d-major), masks =================
template<int MODE>
__global__ __launch_bounds__(256,4) void st_nb(P p){
  __shared__ float s_npW[768], s_npP[384];
  __shared__ ushort s_nb[2][64*136];
  __shared__ float s_valid[2][64];
  int tid=threadIdx.x, g=tid>>7, t=tid&127;
  int b = blockIdx.x*2+g;
  for (int i=tid;i<768;i+=256) s_npW[i]=p.npW[i];
  if (tid<128){ s_npP[tid]=p.npb[tid]; s_npP[128+tid]=p.npg[tid]; s_npP[256+tid]=p.npbb[tid]; }
  __syncthreads();
  int nn=t>>1, jh=t&1;
  float2 pn = ((const float2*)p.npos)[b*N_+nn];
  float2 vn = ((const float2*)p.nvel)[b*N_+nn];
  float2 pe = ((const float2*)p.epos)[b];
  float2 ve = ((const float2*)p.evel)[b];
  float rx=pn.x-pe.x, ry=pn.y-pe.y, rvx=vn.x-ve.x, rvy=vn.y-ve.y;
  float nrm = sqrtf(rx*rx+ry*ry);
  float dist = fmaxf(nrm,1e-6f), bear = atan2f(ry+1e-8f, rx+1e-8f);
  bool vld = (p.mask[b*N_+nn]!=0) && (nrm<3.0f);
  if (jh==0) s_valid[g][nn] = vld?1.f:0.f;
  float z[64]; float sa=0.f, sb=0.f;
  #pragma unroll
  for (int jj=0;jj<64;++jj){
    int j = jh*64+jj;
    float v = s_npP[j] + rx*s_npW[j] + ry*s_npW[128+j] + rvx*s_npW[256+j]
                       + rvy*s_npW[384+j] + dist*s_npW[512+j] + bear*s_npW[640+j];
    z[jj]=v; sa+=v; sb+=v*v;
  }
  sa += __shfl_xor(sa,1); sb += __shfl_xor(sb,1);
  float m1 = sa*0.0078125f, r1 = rsqrtf(sb*0.0078125f - m1*m1 + 1e-5f);
  float ta=0.f, tb=0.f;
  #pragma unroll
  for (int jj=0;jj<64;++jj){
    int j = jh*64+jj;
    float a = (z[jj]-m1)*r1*s_npP[128+j] + s_npP[256+j];
    a = fmaxf(a,0.f);
    z[jj]=a; ta+=a; tb+=a*a;
  }
  ta += __shfl_xor(ta,1); tb += __shfl_xor(tb,1);
  float m2v = ta*0.0078125f, r2 = rsqrtf(tb*0.0078125f - m2v*m2v + 1e-5f);
  uint* gdst = (uint*)(p.nbg + (size_t)b*8192 + nn*128 + jh*64);
  uint* ldst = (uint*)(&s_nb[g][nn*136 + jh*64]);
  #pragma unroll
  for (int q=0;q<32;++q){
    uint pr = pk2((z[2*q]-m2v)*r2, (z[2*q+1]-m2v)*r2);
    gdst[q] = pr; ldst[q] = pr;
  }
  __syncthreads();
  if (tid<2){
    u64 m=0;
    for (int n=0;n<64;++n) if (s_valid[tid][n]>0.5f) m |= (1ULL<<n);
    if (m==0ULL) m = 1ULL;      // all-invalid fixup: neighbor 0 forced valid
    p.msk[blockIdx.x*2+tid] = m;
  }
  if (MODE==2){
    // transpose: thread t -> d'=t, write nbt[b][d'][n]
    uint pk[32];
    #pragma unroll 8
    for (int m=0;m<32;++m){
      ushort lo = s_nb[g][(2*m)*136 + t];
      ushort hi = s_nb[g][(2*m+1)*136 + t];
      pk[m] = (uint)lo | ((uint)hi<<16);
    }
    uint4* dst = (uint4*)(p.nbt + (size_t)b*8192 + t*64);
    #pragma unroll
    for (int q=0;q<8;++q) dst[q] = make_uint4(pk[4*q],pk[4*q+1],pk[4*q+2],pk[4*q+3]);
  }
}

// ================= main fused kernel: 8 batches/block, 4 blocks/CU =================
template<int MODE>
__global__ __launch_bounds__(256,4) void st_main(P p){
  __shared__ __align__(16) char smem[LDS_SZ];
  const int tid = threadIdx.x;
  const int w = tid>>6, l64 = tid&63;
  const int cc = l64&15, qq = l64>>4;
  const int b5 = tid>>5, sg = tid&31;
  const int bB = blockIdx.x*8;

  if (tid<8) ((u64*)(smem+OFF_MSK))[tid] = p.msk[bB+tid];

  // ego input -> XH (bf16)
  {
    const float* src = p.ego + (size_t)(bB+b5)*128 + sg*4;
    float4 v = *(const float4*)src;
    uint2 o; o.x = pk2(v.x,v.y); o.y = pk2(v.z,v.w);
    *(uint2*)(smem + OFF_XH + b5*XHSTR + sg*8) = o;
  }
  __syncthreads();
  // ego GEMM -> X (+ego_b)
  {
    #pragma unroll
    for (int i=0;i<2;++i){
      int nt = w*2+i;
      f32x4 acc = {0.f,0.f,0.f,0.f};
      #pragma unroll
      for (int kt=0;kt<4;++kt){
        FragU a,bF;
        a.u = *(const uint4*)(smem + OFF_XH + (cc&7)*XHSTR + kt*64 + qq*16);
        bF.u = *(const uint4*)(p.egoT + (nt*16+cc)*128 + kt*32 + qq*8);
        acc = __builtin_amdgcn_mfma_f32_16x16x32_bf16(a.h, bF.h, acc, 0,0,0);
      }
      if (qq<2){
        int col = nt*16+cc; float bv = p.ego_b[col];
        #pragma unroll
        for (int r=0;r<4;++r) *(float*)(smem+OFF_X+(qq*4+r)*XSTR+col*4) = acc[r]+bv;
      }
    }
  }
  __syncthreads();
  // ego LN affine in place
  {
    float* xr = (float*)(smem + OFF_X + b5*XSTR + sg*16);
    float4 v = *(float4*)xr;
    float s1 = v.x+v.y+v.z+v.w, s2 = v.x*v.x+v.y*v.y+v.z*v.z+v.w*v.w;
    for (int o=1;o<32;o<<=1){ s1 += __shfl_xor(s1,o); s2 += __shfl_xor(s2,o); }
    float m = s1*0.0078125f, rs = rsqrtf(s2*0.0078125f - m*m + 1e-5f);
    int c0 = sg*4;
    v.x = (v.x-m)*rs*p.ego_g[c0+0]+p.ego_bb[c0+0];
    v.y = (v.y-m)*rs*p.ego_g[c0+1]+p.ego_bb[c0+1];
    v.z = (v.z-m)*rs*p.ego_g[c0+2]+p.ego_bb[c0+2];
    v.w = (v.w-m)*rs*p.ego_g[c0+3]+p.ego_bb[c0+3];
    *(float4*)xr = v;
  }
  __syncthreads();

  for (int li=0; li<L_; ++li){
    // ---- LN(x) -> XH (plain; n1 folded into MT) ----
    {
      const float* xr = (const float*)(smem + OFF_X + b5*XSTR + sg*16);
      float4 v = *(const float4*)xr;
      float s1 = v.x+v.y+v.z+v.w, s2 = v.x*v.x+v.y*v.y+v.z*v.z+v.w*v.w;
      for (int o=1;o<32;o<<=1){ s1 += __shfl_xor(s1,o); s2 += __shfl_xor(s2,o); }
      float m = s1*0.0078125f, rs = rsqrtf(s2*0.0078125f - m*m + 1e-5f);
      uint2 o2; o2.x = pk2((v.x-m)*rs,(v.y-m)*rs); o2.y = pk2((v.z-m)*rs,(v.w-m)*rs);
      *(uint2*)(smem + OFF_XH + b5*XHSTR + sg*8) = o2;
    }
    __syncthreads();
    // ---- qk_all GEMM: N=1024 (h,d), K=128 ----
    {
      const ushort* MTl = p.MT + (size_t)li*131072;
      const float*  C0l = p.C0 + li*1024;
      FragU aF[4];
      #pragma unroll
      for (int kt=0;kt<4;++kt) aF[kt].u = *(const uint4*)(smem + OFF_XH + (cc&7)*XHSTR + kt*64 + qq*16);
      for (int it=0; it<16; ++it){
        int nt = w*16+it;
        f32x4 acc = {0.f,0.f,0.f,0.f};
        #pragma unroll
        for (int kt=0;kt<4;++kt){
          FragU bF; bF.u = *(const uint4*)(MTl + (nt*16+cc)*128 + kt*32 + qq*8);
          acc = __builtin_amdgcn_mfma_f32_16x16x32_bf16(aF[kt].h, bF.h, acc, 0,0,0);
        }
        if (qq<2){
          int col = nt*16+cc; float c0 = C0l[col];
          int h = col>>7, dd = col&127;
          #pragma unroll
          for (int r=0;r<4;++r)
            *(ushort*)(smem + OFF_QKA + (qq*4+r)*2176 + h*272 + dd*2) = f2bf(acc[r]+c0);
        }
      }
    }
    // qb VALU: thread -> (b=tid>>5, h=(tid>>2)&7, q4=tid&3)
    {
      int b_ = tid>>5, h = (tid>>2)&7, q4 = tid&3;
      const ushort* xh = (const ushort*)(smem + OFF_XH + b_*XHSTR);
      const float* m2l = p.m2 + li*1024;
      float a = 0.f;
      #pragma unroll 8
      for (int e = q4*32; e < q4*32+32; ++e) a += bf2f(xh[e]) * m2l[e*8+h];
      a += __shfl_xor(a,1); a += __shfl_xor(a,2);
      if (q4==0) *(float*)(smem + OFF_QB + (b_*8+h)*4) = a + p.c2[li*8+h];
    }
    __syncthreads();

    // ---- attention rounds: per-wave, barrier-free ----
    for (int rr=0; rr<2; ++rr){
      const int bl = w*2+rr;
      const size_t bg = (size_t)(bB+bl);
      const ushort* nbB = p.nbg + bg*8192;
      // B-frags: qk rows (h = cc)
      FragU bq4[4];
      #pragma unroll
      for (int kt=0;kt<4;++kt) bq4[kt].u = *(const uint4*)(smem + OFF_QKA + bl*2176 + cc*272 + kt*64 + qq*16);
      // scores: D[n= mt*16+qq*4+r][h=cc]
      f32x4 c[4];
      #pragma unroll
      for (int mt=0;mt<4;++mt){
        f32x4 acc = {0.f,0.f,0.f,0.f};
        #pragma unroll
        for (int kt=0;kt<4;++kt){
          FragU a; a.u = *(const uint4*)(nbB + (mt*16+cc)*128 + kt*32 + qq*8);
          acc = __builtin_amdgcn_mfma_f32_16x16x32_bf16(a.h, bq4[kt].h, acc, 0,0,0);
        }
        c[mt]=acc;
      }
      float qbv = *(const float*)(smem + OFF_QB + (bl*8+(cc&7))*4);
      u64 vm = ((const u64*)(smem+OFF_MSK))[bl];
      float sc[16];
      #pragma unroll
      for (int mt=0;mt<4;++mt)
        #pragma unroll
        for (int r=0;r<4;++r){
          int n = mt*16 + qq*4 + r;
          bool ok = (vm>>n)&1ULL;
          sc[mt*4+r] = ok ? (c[mt][r]+qbv) : -1e9f;
        }
      float mx = -3e38f;
      #pragma unroll
      for (int k=0;k<16;++k) mx = fmaxf(mx, sc[k]);
      mx = fmaxf(mx,__shfl_xor(mx,16)); mx = fmaxf(mx,__shfl_xor(mx,32));
      float ex[16], se = 0.f;
      #pragma unroll
      for (int k=0;k<16;++k){ ex[k]=__expf(sc[k]-mx); se+=ex[k]; }
      se += __shfl_xor(se,16); se += __shfl_xor(se,32);
      float inv = 1.f/se;
      // pack: P[2*mt+hf] = attn pair (n = mt*16+qq*4+2hf, +1)
      uint P[8];
      #pragma unroll
      for (int mt=0;mt<4;++mt){
        P[2*mt]   = pk2(ex[mt*4+0]*inv, ex[mt*4+1]*inv);
        P[2*mt+1] = pk2(ex[mt*4+2]*inv, ex[mt*4+3]*inv);
      }
      // shfl-transpose -> U A-frags: lane cc=h, k = ktU*32+qq*8+j
      FragU aU[2];
      #pragma unroll
      for (int ktU=0;ktU<2;++ktU){
        uint e[4];
        #pragma unroll
        for (int pp=0;pp<4;++pp){
          int src = (((2*qq + (pp>>1)) & 3) << 4) + cc;
          uint lo = (uint)__shfl((int)P[4*ktU + (pp&1)],     src);
          uint hi = (uint)__shfl((int)P[4*ktU + 2 + (pp&1)], src);
          e[pp] = (qq>>1) ? hi : lo;
        }
        aU[ktU].u = make_uint4(e[0],e[1],e[2],e[3]);
      }
      // U = attn @ nbhat : B rows = d' (from nbt), out rows h (qq<2)
      const ushort* nbT = p.nbt + bg*8192;
      #pragma unroll
      for (int nt=0;nt<8;++nt){
        f32x4 acc = {0.f,0.f,0.f,0.f};
        #pragma unroll
        for (int ktU=0;ktU<2;++ktU){
          FragU bF;
          if (MODE==2){
            bF.u = *(const uint4*)(nbT + (nt*16+cc)*64 + ktU*32 + qq*8);
          } else {
            ushort tmp[8];
            #pragma unroll
            for (int j=0;j<8;++j) tmp[j] = nbB[(ktU*32+qq*8+j)*128 + nt*16+cc];
            uint* tp = (uint*)tmp;
            bF.u = make_uint4(tp[0],tp[1],tp[2],tp[3]);
          }
          acc = __builtin_amdgcn_mfma_f32_16x16x32_bf16(aU[ktU].h, bF.h, acc, 0,0,0);
        }
        if (qq<2){
          #pragma unroll
          for (int r=0;r<4;++r){
            int h = qq*4+r;
            *(ushort*)(smem + OFF_UA + bl*2064 + (h*128 + nt*16+cc)*2) = f2bf(acc[r]);
          }
        }
      }
    } // rounds
    __syncthreads();

    // ---- x += U_all @ G + bo2 : M=8, N=128, K=1024 ----
    {
      const ushort* Gl = p.G + (size_t)li*131072;
      #pragma unroll
      for (int i=0;i<2;++i){
        int nt = w*2+i;
        f32x4 acc = {0.f,0.f,0.f,0.f};
        #pragma unroll 8
        for (int kt=0;kt<32;++kt){
          FragU a,bF;
          a.u = *(const uint4*)(smem + OFF_UA + (cc&7)*2064 + kt*64 + qq*16);
          bF.u = *(const uint4*)(Gl + (nt*16+cc)*1024 + kt*32 + qq*8);
          acc = __builtin_amdgcn_mfma_f32_16x16x32_bf16(a.h, bF.h, acc, 0,0,0);
        }
        if (qq<2){
          int col = nt*16+cc; float bv = p.bo2[li*128+col];
          #pragma unroll
          for (int r=0;r<4;++r){
            float* xp = (float*)(smem + OFF_X + (qq*4+r)*XSTR + col*4);
            *xp += acc[r]+bv;
          }
        }
      }
    }
    __syncthreads();

    // ---- FFN: LN(x) -> XH (n2 folded into W1B) ----
    {
      const float* xr = (const float*)(smem + OFF_X + b5*XSTR + sg*16);
      float4 v = *(const float4*)xr;
      float s1 = v.x+v.y+v.z+v.w, s2 = v.x*v.x+v.y*v.y+v.z*v.z+v.w*v.w;
      for (int o=1;o<32;o<<=1){ s1 += __shfl_xor(s1,o); s2 += __shfl_xor(s2,o); }
      float m = s1*0.0078125f, rs = rsqrtf(s2*0.0078125f - m*m + 1e-5f);
      uint2 o2; o2.x = pk2((v.x-m)*rs,(v.y-m)*rs); o2.y = pk2((v.z-m)*rs,(v.w-m)*rs);
      *(uint2*)(smem + OFF_XH + b5*XHSTR + sg*8) = o2;
    }
    __syncthreads();
    // W1 GEMM + gelu -> H1 (aliases QKA)
    {
      const ushort* W = p.W1B + (size_t)li*65536;
      const float* b1l = p.b1F + li*512;
      FragU aF[4];
      #pragma unroll
      for (int kt=0;kt<4;++kt) aF[kt].u = *(const uint4*)(smem + OFF_XH + (cc&7)*XHSTR + kt*64 + qq*16);
      #pragma unroll
      for (int it=0;it<8;++it){
        int nt = w*8+it;
        f32x4 acc = {0.f,0.f,0.f,0.f};
        #pragma unroll
        for (int kt=0;kt<4;++kt){
          FragU bF; bF.u = *(const uint4*)(W + (nt*16+cc)*128 + kt*32 + qq*8);
          acc = __builtin_amdgcn_mfma_f32_16x16x32_bf16(aF[kt].h, bF.h, acc, 0,0,0);
        }
        if (qq<2){
          int col = nt*16+cc; float bv = b1l[col];
          #pragma unroll
          for (int r=0;r<4;++r){
            float v = acc[r]+bv;
            v = 0.5f*v*(1.f+erff(v*0.70710678118654752f));
            *(ushort*)(smem + OFF_H1 + (qq*4+r)*1040 + col*2) = f2bf(v);
          }
        }
      }
    }
    __syncthreads();
    // W2 GEMM -> X += (K=512)
    {
      const ushort* W = p.W2B + (size_t)li*65536;
      #pragma unroll
      for (int i=0;i<2;++i){
        int nt = w*2+i;
        f32x4 acc = {0.f,0.f,0.f,0.f};
        #pragma unroll 8
        for (int kt=0;kt<16;++kt){
          FragU a,bF;
          a.u = *(const uint4*)(smem + OFF_H1 + (cc&7)*1040 + kt*64 + qq*16);
          bF.u = *(const uint4*)(W + (nt*16+cc)*512 + kt*32 + qq*8);
          acc = __builtin_amdgcn_mfma_f32_16x16x32_bf16(a.h, bF.h, acc, 0,0,0);
        }
        if (qq<2){
          int col = nt*16+cc; float bv = p.b2[li*128+col];
          #pragma unroll
          for (int r=0;r<4;++r){
            float* xp = (float*)(smem + OFF_X + (qq*4+r)*XSTR + col*4);
            *xp += acc[r]+bv;
          }
        }
      }
    }
    __syncthreads();
  } // layers

  // ---- output: LN(x @ outW + out_b) ----
  {
    const float* xr = (const float*)(smem + OFF_X + b5*XSTR + sg*16);
    float4 v = *(const float4*)xr;
    uint2 o2; o2.x = pk2(v.x,v.y); o2.y = pk2(v.z,v.w);
    *(uint2*)(smem + OFF_XH + b5*XHSTR + sg*8) = o2;
  }
  __syncthreads();
  {
    #pragma unroll
    for (int i=0;i<2;++i){
      int nt = w*2+i;
      f32x4 acc = {0.f,0.f,0.f,0.f};
      #pragma unroll
      for (int kt=0;kt<4;++kt){
        FragU a,bF;
        a.u = *(const uint4*)(smem + OFF_XH + (cc&7)*XHSTR + kt*64 + qq*16);
        bF.u = *(const uint4*)(p.outT + (nt*16+cc)*128 + kt*32 + qq*8);
        acc = __builtin_amdgcn_mfma_f32_16x16x32_bf16(a.h, bF.h, acc, 0,0,0);
      }
      if (qq<2){
        int col = nt*16+cc; float bv = p.out_b[col];
        #pragma unroll
        for (int r=0;r<4;++r) *(float*)(smem + OFF_X + (qq*4+r)*XSTR + col*4) = acc[r]+bv;
      }
    }
  }
  __syncthreads();
  {
    const float* xr = (const float*)(smem + OFF_X + b5*XSTR + sg*16);
    float4 v = *(const float4*)xr;
    float s1 = v.x+v.y+v.z+v.w, s2 = v.x*v.x+v.y*v.y+v.z*v.z+v.w*v.w;
    for (int o=1;o<32;o<<=1){ s1 += __shfl_xor(s1,o); s2 += __shfl_xor(s2,o); }
    float m = s1*0.0078125f, rs = rsqrtf(s2*0.0078125f - m*m + 1e-5f);
    int c0 = sg*4;
    float4 o4;
    o4.x = (v.x-m)*rs*p.out_g[c0+0]+p.out_bb[c0+0];
    o4.y = (v.y-m)*rs*p.out_g[c0+1]+p.out_bb[c0+1];
    o4.z = (v.z-m)*rs*p.out_g[c0+2]+p.out_bb[c0+2];
    o4.w = (v.w-m)*rs*p.out_g[c0+3]+p.out_bb[c0+3];
    *(float4*)(p.outp + (size_t)(bB+b5)*128 + sg*4) = o4;
  }
}

// ================= host =================
extern "C" void kernel_launch(void* const* d_in, const int* in_sizes, int n_in,
                              void* d_out, int out_size, void* d_ws, size_t ws_size,
                              hipStream_t stream){
  (void)in_sizes; (void)n_in; (void)out_size;
  char* ws = (char*)d_ws;
  ushort* MT   = (ushort*)(ws + 0);         // 786432
  ushort* G    = (ushort*)(ws + 786432);    // 786432
  ushort* W1B  = (ushort*)(ws + 1572864);   // 393216
  ushort* W2B  = (ushort*)(ws + 1966080);   // 393216
  ushort* egoT = (ushort*)(ws + 2359296);   // 32768
  ushort* outT = (ushort*)(ws + 2392064);   // 32768
  float*  C0   = (float*) (ws + 2424832);   // 12288
  float*  m2   = (float*) (ws + 2437120);   // 12288
  float*  c2   = (float*) (ws + 2449408);   // 128
  float*  bo2  = (float*) (ws + 2449536);   // 1536
  float*  b1F  = (float*) (ws + 2451072);   // 6144
  float*  bqp  = (float*) (ws + 2457216);   // 1536
  float*  bkp  = (float*) (ws + 2458752);   // 1536
  float*  bvp  = (float*) (ws + 2460288);   // 1536
  u64*    msk  = (u64*)   (ws + 2461952);   // 65536
  const size_t NB_OFF = 2527744;
  const size_t NT_OFF = NB_OFF + (size_t)B_*16384;        // +134217728
  const size_t NEED2  = NT_OFF + (size_t)B_*16384;
  const bool mode2 = (ws_size >= NEED2);

  prep_bias<<<11,256,0,stream>>>((const float*)d_in[20],(const float*)d_in[21],(const float*)d_in[15],
                                 (const float*)d_in[22],(const float*)d_in[23],(const float*)d_in[17],
                                 (const float*)d_in[24],(const float*)d_in[25],
                                 (const float*)d_in[28],(const float*)d_in[29],(const float*)d_in[19],
                                 bqp,bkp,bvp,b1F);
  prep_bias2<<<3,256,0,stream>>>((const float*)d_in[26],(const float*)d_in[27],bvp,bo2);
  prep_MG<<<24,256,0,stream>>>((const float*)d_in[20],(const float*)d_in[22],(const float*)d_in[24],(const float*)d_in[26],
                               (const float*)d_in[14],(const float*)d_in[16],
                               bqp,bkp, MT,C0,m2,c2,G);
  prep_T<<<1664,256,0,stream>>>((const float*)d_in[28],(const float*)d_in[18],(const float*)d_in[30],
                                (const float*)d_in[10],(const float*)d_in[32],
                                W1B,W2B,egoT,outT);
  P p;
  p.ego=(const float*)d_in[0]; p.epos=(const float*)d_in[1]; p.evel=(const float*)d_in[2];
  p.npos=(const float*)d_in[3]; p.nvel=(const float*)d_in[4]; p.mask=(const int*)d_in[5];
  p.npW=(const float*)d_in[6]; p.npb=(const float*)d_in[7]; p.npg=(const float*)d_in[8]; p.npbb=(const float*)d_in[9];
  p.ego_b=(const float*)d_in[11]; p.ego_g=(const float*)d_in[12]; p.ego_bb=(const float*)d_in[13];
  p.b2=(const float*)d_in[31];
  p.out_b=(const float*)d_in[33]; p.out_g=(const float*)d_in[34]; p.out_bb=(const float*)d_in[35];
  p.C0=C0; p.m2=m2; p.c2=c2; p.bo2=bo2; p.b1F=b1F;
  p.MT=MT; p.G=G; p.W1B=W1B; p.W2B=W2B; p.egoT=egoT; p.outT=outT;
  p.nbg=(ushort*)(ws+NB_OFF); p.nbt=(ushort*)(ws+NT_OFF); p.msk=msk;
  p.outp=(float*)d_out;

  if (mode2){
    st_nb<2><<<B_/2,256,0,stream>>>(p);
    st_main<2><<<B_/8,256,0,stream>>>(p);
  } else {
    st_nb<1><<<B_/2,256,0,stream>>>(p);
    st_main<1><<<B_/8,256,0,stream>>>(p);
  }
}

// Round 5
// 1140.582 us; speedup vs baseline: 1.1088x; 1.1088x over previous
//
#include <hip/hip_runtime.h>
#include <stdint.h>

typedef unsigned int uint;
typedef unsigned short ushort;
typedef unsigned long long u64;

#define B_   8192
#define D_   128
#define N_   64
#define L_   3

typedef __attribute__((ext_vector_type(8))) short short8;
typedef __attribute__((ext_vector_type(4))) float f32x4;
union FragU { uint4 u; short8 h; };

__device__ __forceinline__ float bf2f(ushort u){ union{uint i; float f;} c; c.i=((uint)u)<<16; return c.f; }
__device__ __forceinline__ float bflo(uint u){ union{uint i; float f;} c; c.i=u<<16; return c.f; }
__device__ __forceinline__ float bfhi(uint u){ union{uint i; float f;} c; c.i=u&0xffff0000u; return c.f; }
__device__ __forceinline__ ushort f2bf(float f){ uint u=__float_as_uint(f); return (ushort)((u + 0x7fffu + ((u>>16)&1u))>>16); }
__device__ __forceinline__ uint pk2(float lo, float hi){ return (uint)f2bf(lo) | (((uint)f2bf(hi))<<16); }

// ---------------- LDS layout (bytes), 4 batches/block ----------------
#define OFF_NPW  0        // f32 [6][128]           3072
#define OFF_NPP  3072     // f32 [3][128]           1536 (npb, npg, npbb)
#define OFF_REL  4608     // f32 [4][64][6]         6144
#define OFF_MSK  10752    // u64 [4]                32
#define OFF_X    10784    // f32 [4][132]           2112 (stride 528)
#define XSTR     528
#define OFF_XH   12896    // bf16 [4][136]          1088 (stride 272)
#define XHSTR    272
#define OFF_QKA  13984    // bf16 [4 b][8 h][136]   8704 (b-stride 2176, h-stride 272)
#define OFF_H1   13984    // bf16 [4][520] (stride 1040) — aliases QKA in FFN phase
#define OFF_QB   22688    // f32 [4][8]             128
#define OFF_SL   22816    // nbhat slice bf16 [64][132] 16896 (stride 264)
#define SLSTR    264
#define OFF_ATT  39712    // f32 [8][64]            2048
#define OFF_UA   41760    // bf16 [4][1024+8]       8256 (stride 2064)
#define LDS_SZ   50048

struct P {
  const float *ego,*epos,*evel,*npos,*nvel;
  const int   *mask;
  const float *npW,*npb,*npg,*npbb;
  const float *ego_b,*ego_g,*ego_bb;
  const float *b2,*out_b,*out_g,*out_bb;
  const float *C0,*m2,*c2,*bo2,*b1F;
  const ushort *MT,*G,*W1B,*W2B,*egoT,*outT;
  float *outp;
};

// ================= prep kernels (proven in R4, absmax 0.031) =================
__global__ void prep_bias(const float* Wq,const float* bq,const float* n1b,
                          const float* Wk,const float* bk,const float* nkb,
                          const float* Wv,const float* bv,
                          const float* W1,const float* b1,const float* n2b,
                          float* bqp, float* bkp, float* bvp, float* b1F){
  int gid = blockIdx.x*256 + threadIdx.x;
  if (gid >= 3*896) return;
  int l = gid/896, c = gid%896;
  if (c < 384){
    int m = c>>7, j = c&127;
    const float* W = (m==0?Wq:(m==1?Wk:Wv)) + l*16384 + j;
    const float* nb = (m==0? n1b : nkb) + l*128;
    const float* bs = (m==0?bq:(m==1?bk:bv)) + l*128 + j;
    float a = *bs;
    for (int e=0;e<128;++e) a += nb[e]*W[e*128];
    float* dst = (m==0?bqp:(m==1?bkp:bvp));
    dst[l*128+j] = a;
  } else {
    int f = c-384;
    float a = b1[l*512+f];
    const float* W = W1 + l*65536 + f;
    const float* nb = n2b + l*128;
    for (int e=0;e<128;++e) a += nb[e]*W[e*512];
    b1F[l*512+f] = a;
  }
}

__global__ void prep_bias2(const float* Wo, const float* bo, const float* bvp, float* bo2){
  int l = blockIdx.x, t = threadIdx.x;
  if (t < 128){
    float a = bo[l*128+t];
    const float* W = Wo + l*16384 + t;
    const float* bv = bvp + l*128;
    for (int c=0;c<128;++c) a += bv[c]*W[c*128];
    bo2[l*128+t] = a;
  }
}

__global__ void prep_MG(const float* Wq,const float* Wk,const float* Wv,const float* Wo,
                        const float* n1g,const float* nkg,
                        const float* bqp,const float* bkp,
                        ushort* MT, float* C0, float* m2, float* c2, ushort* G){
  __shared__ float sWq[128][16], sWk[128][16], sWv[128][16], sWo[16][128];
  int l = blockIdx.x>>3, h = blockIdx.x&7, t = threadIdx.x;
  { int row = t>>1, hf = t&1;
    const float* q = Wq + l*16384 + row*128 + h*16 + hf*8;
    const float* k = Wk + l*16384 + row*128 + h*16 + hf*8;
    const float* v = Wv + l*16384 + row*128 + h*16 + hf*8;
    for (int j=0;j<8;++j){ sWq[row][hf*8+j]=q[j]; sWk[row][hf*8+j]=k[j]; sWv[row][hf*8+j]=v[j]; }
  }
  { int row = t>>4, sg = t&15;
    const float* o = Wo + l*16384 + (h*16+row)*128 + sg*8;
    for (int j=0;j<8;++j) sWo[row][sg*8+j]=o[j];
  }
  __syncthreads();
  {
    int e = t&127;
    float g1 = 0.25f*n1g[l*128+e];
    float wq[16];
    #pragma unroll
    for (int j=0;j<16;++j) wq[j]=sWq[e][j];
    for (int k2=0;k2<64;++k2){
      int d = (t>>7) + 2*k2;
      float s=0.f;
      #pragma unroll
      for (int j=0;j<16;++j) s += wq[j]*sWk[d][j];
      MT[(size_t)l*131072 + (size_t)(h*128+d)*128 + e] = f2bf(g1*nkg[l*128+d]*s);
    }
    if (t<128){
      float s=0.f;
      #pragma unroll
      for (int j=0;j<16;++j) s += wq[j]*bkp[l*128+h*16+j];
      m2[(l*128+e)*8+h] = g1*s;
    }
  }
  if (t<128){
    int d=t; float s=0.f;
    #pragma unroll
    for (int j=0;j<16;++j) s += bqp[l*128+h*16+j]*sWk[d][j];
    C0[l*1024 + h*128 + d] = 0.25f*nkg[l*128+d]*s;
  }
  if (t==0){
    float s=0.f;
    for (int j=0;j<16;++j) s += bqp[l*128+h*16+j]*bkp[l*128+h*16+j];
    c2[l*8+h] = 0.25f*s;
  }
  {
    int d = t&127;
    float gk = nkg[l*128+d];
    float wv[16];
    #pragma unroll
    for (int j=0;j<16;++j) wv[j]=gk*sWv[d][j];
    for (int k2=0;k2<64;++k2){
      int e = (t>>7) + 2*k2;
      float s=0.f;
      #pragma unroll
      for (int j=0;j<16;++j) s += wv[j]*sWo[j][e];
      G[(size_t)l*131072 + (size_t)e*1024 + h*128 + d] = f2bf(s);
    }
  }
}

__global__ void prep_T(const float* W1,const float* n2g,const float* W2,
                       const float* egoW,const float* outW,
                       ushort* W1B, ushort* W2B, ushort* egoT, ushort* outT){
  int gid = blockIdx.x*256 + threadIdx.x;
  if (gid < 196608){
    int l = gid/65536, r = gid%65536, f = r>>7, e = r&127;
    W1B[gid] = f2bf(n2g[l*128+e]*W1[l*65536 + e*512 + f]);
  } else if (gid < 393216){
    int q = gid-196608; int l = q/65536, r = q%65536, e = r>>9, f = r&511;
    W2B[q] = f2bf(W2[l*65536 + f*128 + e]);
  } else if (gid < 409600){
    int q = gid-393216; int c = q>>7, e = q&127;
    egoT[q] = f2bf(egoW[e*128+c]);
  } else if (gid < 425984){
    int q = gid-409600; int c = q>>7, e = q&127;
    outT[q] = f2bf(outW[e*128+c]);
  }
}

// ================= main fused kernel: 4 batches/block =================
__global__ __launch_bounds__(256,3) void st_main(P p){
  __shared__ __align__(16) char smem[LDS_SZ];
  const int tid = threadIdx.x;
  const int w = tid>>6, l64 = tid&63;
  const int cc = l64&15, qq = l64>>4;
  const int bB = blockIdx.x*4;

  // ---- pre-loop: np params, rel features, masks, ego input ----
  for (int i=tid;i<768;i+=256) ((float*)(smem+OFF_NPW))[i] = p.npW[i];
  if (tid<128){
    ((float*)(smem+OFF_NPP))[tid]     = p.npb[tid];
    ((float*)(smem+OFF_NPP))[128+tid] = p.npg[tid];
    ((float*)(smem+OFF_NPP))[256+tid] = p.npbb[tid];
  }
  {
    const int b = bB + w, n = l64;
    float2 pn = ((const float2*)p.npos)[b*N_+n];
    float2 vn = ((const float2*)p.nvel)[b*N_+n];
    float2 pe = ((const float2*)p.epos)[b];
    float2 ve = ((const float2*)p.evel)[b];
    float rx=pn.x-pe.x, ry=pn.y-pe.y, rvx=vn.x-ve.x, rvy=vn.y-ve.y;
    float nrm = sqrtf(rx*rx+ry*ry);
    float dist = fmaxf(nrm,1e-6f), bear = atan2f(ry+1e-8f, rx+1e-8f);
    bool vld = (p.mask[b*N_+n]!=0) && (nrm<3.0f);
    u64 bal = __ballot(vld);
    if (bal==0ULL) bal = 1ULL;     // all-invalid fixup: neighbor 0 forced valid
    if (l64==0) ((u64*)(smem+OFF_MSK))[w] = bal;
    float* rl = (float*)(smem + OFF_REL + w*1536 + n*24);
    rl[0]=rx; rl[1]=ry; rl[2]=rvx; rl[3]=rvy; rl[4]=dist; rl[5]=bear;
  }
  {
    float2 v = *(const float2*)(p.ego + (size_t)(bB+w)*128 + 2*l64);
    *(uint*)(smem + OFF_XH + w*XHSTR + l64*4) = pk2(v.x,v.y);
  }
  __syncthreads();

  // ---- ego GEMM -> X (+ego_b) ----
  {
    #pragma unroll
    for (int i=0;i<2;++i){
      int nt = w*2+i;
      f32x4 acc = {0.f,0.f,0.f,0.f};
      #pragma unroll
      for (int kt=0;kt<4;++kt){
        FragU a,bF;
        a.u = *(const uint4*)(smem + OFF_XH + (cc&3)*XHSTR + kt*64 + qq*16);
        bF.u = *(const uint4*)(p.egoT + (nt*16+cc)*128 + kt*32 + qq*8);
        acc = __builtin_amdgcn_mfma_f32_16x16x32_bf16(a.h, bF.h, acc, 0,0,0);
      }
      if (qq==0){
        int col = nt*16+cc; float bv = p.ego_b[col];
        #pragma unroll
        for (int r=0;r<4;++r) *(float*)(smem+OFF_X+r*XSTR+col*4) = acc[r]+bv;
      }
    }
  }
  __syncthreads();
  // ego LN affine in place (wave w = batch w)
  {
    float* xr = (float*)(smem + OFF_X + w*XSTR);
    float2 v = *(float2*)(xr + 2*l64);
    float s1 = v.x+v.y, s2 = v.x*v.x+v.y*v.y;
    for (int o=1;o<64;o<<=1){ s1 += __shfl_xor(s1,o); s2 += __shfl_xor(s2,o); }
    float m = s1*0.0078125f, rs = rsqrtf(s2*0.0078125f - m*m + 1e-5f);
    int c0 = 2*l64;
    v.x = (v.x-m)*rs*p.ego_g[c0]+p.ego_bb[c0];
    v.y = (v.y-m)*rs*p.ego_g[c0+1]+p.ego_bb[c0+1];
    *(float2*)(xr + 2*l64) = v;
  }
  __syncthreads();

  for (int li=0; li<L_; ++li){
    // ---- LN(x) -> XH (n1 folded into MT) ----
    {
      const float* xr = (const float*)(smem + OFF_X + w*XSTR);
      float2 v = *(const float2*)(xr + 2*l64);
      float s1 = v.x+v.y, s2 = v.x*v.x+v.y*v.y;
      for (int o=1;o<64;o<<=1){ s1 += __shfl_xor(s1,o); s2 += __shfl_xor(s2,o); }
      float m = s1*0.0078125f, rs = rsqrtf(s2*0.0078125f - m*m + 1e-5f);
      *(uint*)(smem + OFF_XH + w*XHSTR + l64*4) = pk2((v.x-m)*rs,(v.y-m)*rs);
    }
    __syncthreads();
    // ---- qk_all GEMM: N=1024, K=128 ----
    {
      const ushort* MTl = p.MT + (size_t)li*131072;
      const float*  C0l = p.C0 + li*1024;
      FragU aF[4];
      #pragma unroll
      for (int kt=0;kt<4;++kt) aF[kt].u = *(const uint4*)(smem + OFF_XH + (cc&3)*XHSTR + kt*64 + qq*16);
      for (int it=0; it<16; ++it){
        int nt = w*16+it;
        f32x4 acc = {0.f,0.f,0.f,0.f};
        #pragma unroll
        for (int kt=0;kt<4;++kt){
          FragU bF; bF.u = *(const uint4*)(MTl + (nt*16+cc)*128 + kt*32 + qq*8);
          acc = __builtin_amdgcn_mfma_f32_16x16x32_bf16(aF[kt].h, bF.h, acc, 0,0,0);
        }
        if (qq==0){
          int col = nt*16+cc; float c0 = C0l[col];
          int h = col>>7, dd = col&127;
          #pragma unroll
          for (int r=0;r<4;++r)
            *(ushort*)(smem + OFF_QKA + r*2176 + h*272 + dd*2) = f2bf(acc[r]+c0);
        }
      }
    }
    // qb: wave w = batch w; h = l64>>3, q8 = l64&7
    {
      int h = l64>>3, q8 = l64&7;
      const ushort* xh = (const ushort*)(smem + OFF_XH + w*XHSTR);
      const float* m2l = p.m2 + li*1024;
      float a = 0.f;
      #pragma unroll 4
      for (int e = q8*16; e < q8*16+16; ++e) a += bf2f(xh[e]) * m2l[e*8+h];
      a += __shfl_xor(a,1); a += __shfl_xor(a,2); a += __shfl_xor(a,4);
      if (q8==0) *(float*)(smem + OFF_QB + (w*8+h)*4) = a + p.c2[li*8+h];
    }
    __syncthreads();

    // ---- attention rounds: 1 batch/round, block-cooperative ----
    for (int bl=0; bl<4; ++bl){
      // (a) recompute nbhat -> slice (block-split: n = w*16 + l64>>2, jq = l64&3)
      {
        const int n = w*16 + (l64>>2), jq = l64&3;
        const float* rl = (const float*)(smem + OFF_REL + bl*1536 + n*24);
        float rx=rl[0], ry=rl[1], rvx=rl[2], rvy=rl[3], dist=rl[4], bear=rl[5];
        const float* W0 = (const float*)(smem + OFF_NPW);
        const float* PP = (const float*)(smem + OFF_NPP);
        float z[32]; float sa=0.f, sb=0.f;
        #pragma unroll
        for (int jj=0;jj<32;++jj){
          int j = jq*32+jj;
          float v = PP[j] + rx*W0[j] + ry*W0[128+j] + rvx*W0[256+j]
                          + rvy*W0[384+j] + dist*W0[512+j] + bear*W0[640+j];
          z[jj]=v; sa+=v; sb+=v*v;
        }
        sa += __shfl_xor(sa,1); sb += __shfl_xor(sb,1);
        sa += __shfl_xor(sa,2); sb += __shfl_xor(sb,2);
        float m1 = sa*0.0078125f, r1 = rsqrtf(sb*0.0078125f - m1*m1 + 1e-5f);
        float ta=0.f, tb=0.f;
        #pragma unroll
        for (int jj=0;jj<32;++jj){
          int j = jq*32+jj;
          float a = (z[jj]-m1)*r1*PP[128+j] + PP[256+j];
          a = fmaxf(a,0.f);
          z[jj]=a; ta+=a; tb+=a*a;
        }
        ta += __shfl_xor(ta,1); tb += __shfl_xor(tb,1);
        ta += __shfl_xor(ta,2); tb += __shfl_xor(tb,2);
        float m2v = ta*0.0078125f, r2 = rsqrtf(tb*0.0078125f - m2v*m2v + 1e-5f);
        uint* dst = (uint*)(smem + OFF_SL + n*SLSTR + jq*64);
        #pragma unroll
        for (int q=0;q<16;++q) dst[q] = pk2((z[2*q]-m2v)*r2, (z[2*q+1]-m2v)*r2);
      }
      __syncthreads();

      // (c) scores MFMA (all waves redundant) + softmax
      float ex[16]; float inv;
      {
        FragU bq4[4];
        #pragma unroll
        for (int kt=0;kt<4;++kt) bq4[kt].u = *(const uint4*)(smem + OFF_QKA + bl*2176 + cc*272 + kt*64 + qq*16);
        f32x4 c[4];
        #pragma unroll
        for (int mt=0;mt<4;++mt){
          f32x4 acc = {0.f,0.f,0.f,0.f};
          #pragma unroll
          for (int kt=0;kt<4;++kt){
            FragU a;
            uint2 lo = *(const uint2*)(smem + OFF_SL + (mt*16+cc)*SLSTR + kt*64 + qq*16);
            uint2 hi = *(const uint2*)(smem + OFF_SL + (mt*16+cc)*SLSTR + kt*64 + qq*16 + 8);
            a.u = make_uint4(lo.x, lo.y, hi.x, hi.y);
            acc = __builtin_amdgcn_mfma_f32_16x16x32_bf16(a.h, bq4[kt].h, acc, 0,0,0);
          }
          c[mt]=acc;
        }
        float qbv = *(const float*)(smem + OFF_QB + (bl*8+(cc&7))*4);
        u64 vm = ((const u64*)(smem+OFF_MSK))[bl];
        float sc[16];
        #pragma unroll
        for (int mt=0;mt<4;++mt)
          #pragma unroll
          for (int r=0;r<4;++r){
            int n = mt*16 + qq*4 + r;
            bool ok = (vm>>n)&1ULL;
            sc[mt*4+r] = ok ? (c[mt][r]+qbv) : -1e9f;
          }
        float mx = -3e38f;
        #pragma unroll
        for (int k=0;k<16;++k) mx = fmaxf(mx, sc[k]);
        mx = fmaxf(mx,__shfl_xor(mx,16)); mx = fmaxf(mx,__shfl_xor(mx,32));
        float se = 0.f;
        #pragma unroll
        for (int k=0;k<16;++k){ ex[k]=__expf(sc[k]-mx); se+=ex[k]; }
        se += __shfl_xor(se,16); se += __shfl_xor(se,32);
        inv = 1.f/se;
      }
      // (d) attn broadcast to LDS (wave 0, h=cc<8)
      if (w==0 && cc<8){
        float* A = (float*)(smem+OFF_ATT);
        #pragma unroll
        for (int mt=0;mt<4;++mt)
          #pragma unroll
          for (int r=0;r<4;++r) A[cc*64 + (mt*16+qq*4+r)] = ex[mt*4+r]*inv;
      }
      __syncthreads();

      // (e) U via VALU: lane = d-pair (l64), wave = h-pair (2w, 2w+1)
      {
        const int h0 = 2*w, h1 = 2*w+1;
        const float* att = (const float*)(smem + OFF_ATT);
        float u00=0.f,u01=0.f,u10=0.f,u11=0.f;
        #pragma unroll 8
        for (int n=0;n<N_;++n){
          uint pr = *(const uint*)(smem + OFF_SL + n*SLSTR + l64*4);
          float flo = bflo(pr), fhi = bfhi(pr);
          float a0 = att[h0*64+n], a1 = att[h1*64+n];
          u00 += a0*flo; u01 += a0*fhi; u10 += a1*flo; u11 += a1*fhi;
        }
        uint* ua = (uint*)(smem + OFF_UA + bl*2064);
        ua[h0*64 + l64] = pk2(u00,u01);
        ua[h1*64 + l64] = pk2(u10,u11);
      }
      __syncthreads();
    } // rounds

    // ---- x += U_all @ G + bo2 : M=4, N=128, K=1024 ----
    {
      const ushort* Gl = p.G + (size_t)li*131072;
      #pragma unroll
      for (int i=0;i<2;++i){
        int nt = w*2+i;
        f32x4 acc = {0.f,0.f,0.f,0.f};
        #pragma unroll 8
        for (int kt=0;kt<32;++kt){
          FragU a,bF;
          a.u = *(const uint4*)(smem + OFF_UA + (cc&3)*2064 + kt*64 + qq*16);
          bF.u = *(const uint4*)(Gl + (nt*16+cc)*1024 + kt*32 + qq*8);
          acc = __builtin_amdgcn_mfma_f32_16x16x32_bf16(a.h, bF.h, acc, 0,0,0);
        }
        if (qq==0){
          int col = nt*16+cc; float bv = p.bo2[li*128+col];
          #pragma unroll
          for (int r=0;r<4;++r){
            float* xp = (float*)(smem + OFF_X + r*XSTR + col*4);
            *xp += acc[r]+bv;
          }
        }
      }
    }
    __syncthreads();

    // ---- FFN: LN(x) -> XH (n2 folded into W1B) ----
    {
      const float* xr = (const float*)(smem + OFF_X + w*XSTR);
      float2 v = *(const float2*)(xr + 2*l64);
      float s1 = v.x+v.y, s2 = v.x*v.x+v.y*v.y;
      for (int o=1;o<64;o<<=1){ s1 += __shfl_xor(s1,o); s2 += __shfl_xor(s2,o); }
      float m = s1*0.0078125f, rs = rsqrtf(s2*0.0078125f - m*m + 1e-5f);
      *(uint*)(smem + OFF_XH + w*XHSTR + l64*4) = pk2((v.x-m)*rs,(v.y-m)*rs);
    }
    __syncthreads();
    // W1 GEMM + gelu -> H1 (aliases QKA)
    {
      const ushort* W = p.W1B + (size_t)li*65536;
      const float* b1l = p.b1F + li*512;
      FragU aF[4];
      #pragma unroll
      for (int kt=0;kt<4;++kt) aF[kt].u = *(const uint4*)(smem + OFF_XH + (cc&3)*XHSTR + kt*64 + qq*16);
      #pragma unroll
      for (int it=0;it<8;++it){
        int nt = w*8+it;
        f32x4 acc = {0.f,0.f,0.f,0.f};
        #pragma unroll
        for (int kt=0;kt<4;++kt){
          FragU bF; bF.u = *(const uint4*)(W + (nt*16+cc)*128 + kt*32 + qq*8);
          acc = __builtin_amdgcn_mfma_f32_16x16x32_bf16(aF[kt].h, bF.h, acc, 0,0,0);
        }
        if (qq==0){
          int col = nt*16+cc; float bv = b1l[col];
          #pragma unroll
          for (int r=0;r<4;++r){
            float v = acc[r]+bv;
            v = 0.5f*v*(1.f+erff(v*0.70710678118654752f));
            *(ushort*)(smem + OFF_H1 + r*1040 + col*2) = f2bf(v);
          }
        }
      }
    }
    __syncthreads();
    // W2 GEMM -> X += (K=512)
    {
      const ushort* W = p.W2B + (size_t)li*65536;
      #pragma unroll
      for (int i=0;i<2;++i){
        int nt = w*2+i;
        f32x4 acc = {0.f,0.f,0.f,0.f};
        #pragma unroll 8
        for (int kt=0;kt<16;++kt){
          FragU a,bF;
          a.u = *(const uint4*)(smem + OFF_H1 + (cc&3)*1040 + kt*64 + qq*16);
          bF.u = *(const uint4*)(W + (nt*16+cc)*512 + kt*32 + qq*8);
          acc = __builtin_amdgcn_mfma_f32_16x16x32_bf16(a.h, bF.h, acc, 0,0,0);
        }
        if (qq==0){
          int col = nt*16+cc; float bv = p.b2[li*128+col];
          #pragma unroll
          for (int r=0;r<4;++r){
            float* xp = (float*)(smem + OFF_X + r*XSTR + col*4);
            *xp += acc[r]+bv;
          }
        }
      }
    }
    __syncthreads();
  } // layers

  // ---- output: LN(x @ outW + out_b) ----
  {
    const float* xr = (const float*)(smem + OFF_X + w*XSTR);
    float2 v = *(const float2*)(xr + 2*l64);
    *(uint*)(smem + OFF_XH + w*XHSTR + l64*4) = pk2(v.x,v.y);
  }
  __syncthreads();
  {
    #pragma unroll
    for (int i=0;i<2;++i){
      int nt = w*2+i;
      f32x4 acc = {0.f,0.f,0.f,0.f};
      #pragma unroll
      for (int kt=0;kt<4;++kt){
        FragU a,bF;
        a.u = *(const uint4*)(smem + OFF_XH + (cc&3)*XHSTR + kt*64 + qq*16);
        bF.u = *(const uint4*)(p.outT + (nt*16+cc)*128 + kt*32 + qq*8);
        acc = __builtin_amdgcn_mfma_f32_16x16x32_bf16(a.h, bF.h, acc, 0,0,0);
      }
      if (qq==0){
        int col = nt*16+cc; float bv = p.out_b[col];
        #pragma unroll
        for (int r=0;r<4;++r) *(float*)(smem + OFF_X + r*XSTR + col*4) = acc[r]+bv;
      }
    }
  }
  __syncthreads();
  {
    const float* xr = (const float*)(smem + OFF_X + w*XSTR);
    float2 v = *(const float2*)(xr + 2*l64);
    float s1 = v.x+v.y, s2 = v.x*v.x+v.y*v.y;
    for (int o=1;o<64;o<<=1){ s1 += __shfl_xor(s1,o); s2 += __shfl_xor(s2,o); }
    float m = s1*0.0078125f, rs = rsqrtf(s2*0.0078125f - m*m + 1e-5f);
    int c0 = 2*l64;
    float2 o2;
    o2.x = (v.x-m)*rs*p.out_g[c0]+p.out_bb[c0];
    o2.y = (v.y-m)*rs*p.out_g[c0+1]+p.out_bb[c0+1];
    *(float2*)(p.outp + (size_t)(bB+w)*128 + 2*l64) = o2;
  }
}

// ================= host =================
extern "C" void kernel_launch(void* const* d_in, const int* in_sizes, int n_in,
                              void* d_out, int out_size, void* d_ws, size_t ws_size,
                              hipStream_t stream){
  (void)in_sizes; (void)n_in; (void)out_size; (void)ws_size;
  char* ws = (char*)d_ws;
  ushort* MT   = (ushort*)(ws + 0);         // 786432
  ushort* G    = (ushort*)(ws + 786432);    // 786432
  ushort* W1B  = (ushort*)(ws + 1572864);   // 393216
  ushort* W2B  = (ushort*)(ws + 1966080);   // 393216
  ushort* egoT = (ushort*)(ws + 2359296);   // 32768
  ushort* outT = (ushort*)(ws + 2392064);   // 32768
  float*  C0   = (float*) (ws + 2424832);   // 12288
  float*  m2   = (float*) (ws + 2437120);   // 12288
  float*  c2   = (float*) (ws + 2449408);   // 128
  float*  bo2  = (float*) (ws + 2449536);   // 1536
  float*  b1F  = (float*) (ws + 2451072);   // 6144
  float*  bqp  = (float*) (ws + 2457216);   // 1536
  float*  bkp  = (float*) (ws + 2458752);   // 1536
  float*  bvp  = (float*) (ws + 2460288);   // 1536

  prep_bias<<<11,256,0,stream>>>((const float*)d_in[20],(const float*)d_in[21],(const float*)d_in[15],
                                 (const float*)d_in[22],(const float*)d_in[23],(const float*)d_in[17],
                                 (const float*)d_in[24],(const float*)d_in[25],
                                 (const float*)d_in[28],(const float*)d_in[29],(const float*)d_in[19],
                                 bqp,bkp,bvp,b1F);
  prep_bias2<<<3,256,0,stream>>>((const float*)d_in[26],(const float*)d_in[27],bvp,bo2);
  prep_MG<<<24,256,0,stream>>>((const float*)d_in[20],(const float*)d_in[22],(const float*)d_in[24],(const float*)d_in[26],
                               (const float*)d_in[14],(const float*)d_in[16],
                               bqp,bkp, MT,C0,m2,c2,G);
  prep_T<<<1664,256,0,stream>>>((const float*)d_in[28],(const float*)d_in[18],(const float*)d_in[30],
                                (const float*)d_in[10],(const float*)d_in[32],
                                W1B,W2B,egoT,outT);
  P p;
  p.ego=(const float*)d_in[0]; p.epos=(const float*)d_in[1]; p.evel=(const float*)d_in[2];
  p.npos=(const float*)d_in[3]; p.nvel=(const float*)d_in[4]; p.mask=(const int*)d_in[5];
  p.npW=(const float*)d_in[6]; p.npb=(const float*)d_in[7]; p.npg=(const float*)d_in[8]; p.npbb=(const float*)d_in[9];
  p.ego_b=(const float*)d_in[11]; p.ego_g=(const float*)d_in[12]; p.ego_bb=(const float*)d_in[13];
  p.b2=(const float*)d_in[31];
  p.out_b=(const float*)d_in[33]; p.out_g=(const float*)d_in[34]; p.out_bb=(const float*)d_in[35];
  p.C0=C0; p.m2=m2; p.c2=c2; p.bo2=bo2; p.b1F=b1F;
  p.MT=MT; p.G=G; p.W1B=W1B; p.W2B=W2B; p.egoT=egoT; p.outT=outT;
  p.outp=(float*)d_out;

  st_main<<<B_/4,256,0,stream>>>(p);
}

// Round 8
// 676.130 us; speedup vs baseline: 1.8705x; 1.6869x over previous
//
#include <hip/hip_runtime.h>
#include <stdint.h>

typedef unsigned int uint;
typedef unsigned short ushort;
typedef unsigned long long u64;

#define B_   8192
#define D_   128
#define N_   64
#define L_   3

typedef __attribute__((ext_vector_type(8))) short short8;
typedef __attribute__((ext_vector_type(4))) float f32x4;
union FragU { uint4 u; short8 h; };

__device__ __forceinline__ float bf2f(ushort u){ union{uint i; float f;} c; c.i=((uint)u)<<16; return c.f; }
__device__ __forceinline__ float bflo(uint u){ union{uint i; float f;} c; c.i=u<<16; return c.f; }
__device__ __forceinline__ float bfhi(uint u){ union{uint i; float f;} c; c.i=u&0xffff0000u; return c.f; }
__device__ __forceinline__ ushort f2bf(float f){ uint u=__float_as_uint(f); return (ushort)((u + 0x7fffu + ((u>>16)&1u))>>16); }
__device__ __forceinline__ uint pk2(float lo, float hi){ return (uint)f2bf(lo) | (((uint)f2bf(hi))<<16); }

// ---------------- LDS layout (bytes), 8 batches/block, 2 blocks/CU ----------------
#define OFF_NPW  0        // f32 [6][128]              3072
#define OFF_NPP  3072     // f32 [3][128]              1536 (npb, npg, npbb)
#define OFF_X    4608     // x residual f32 [8][132]   4224 (stride 528)
#define XSTR     528
#define OFF_XH   8832     // bf16 [8][136]             2176 (stride 272)
#define XHSTR    272
#define OFF_Q    11008    // Q' bf16 [8][136]          2176
#define OFF_QKA  13184    // qk bf16 [8 b][8 h][136]   17408 (b-str 2176, h-str 272) — aliased by H1 [8][520] str 1040
#define OFF_QB   30592    // f32 [8 b][8 h]            256
#define OFF_MSK  30848    // u64 [8]                   64
#define OFF_SL   30912    // nbhat n-major bf16 [64][132]  16896 (stride 264)
#define SLSTR    264
#define OFF_ATT  47808    // attn f32 [8 h][64 n]      2048
#define OFF_CX   49856    // ctx bf16 [8][136]         2176 (stride 272)
#define OFF_UA   52032    // U bf16 [8 b][1032]        16512 (stride 2064)
#define UASTR    2064
#define LDS_SZ   68544

struct P {
  const float *ego;
  const float *ego_b,*ego_g,*ego_bb;
  const float *npW,*npb,*npg,*npbb;
  const float *bo,*b2,*out_b,*out_g,*out_bb;
  const float *bqp,*bkp,*bvp,*b1F;
  const ushort *WqB,*WkB,*WvB,*WoB,*W1B,*W2B,*egoB,*outB;
  const float *rel; const u64 *msk;
  float *outp;
};

// ================= prep: bias folds (verified R4/R5) =================
__global__ void prep_bias(const float* Wq,const float* bq,const float* n1b,
                          const float* Wk,const float* bk,const float* nkb,
                          const float* Wv,const float* bv,
                          const float* W1,const float* b1,const float* n2b,
                          float* bqp, float* bkp, float* bvp, float* b1F){
  int gid = blockIdx.x*256 + threadIdx.x;
  if (gid >= 3*896) return;
  int l = gid/896, c = gid%896;
  if (c < 384){
    int m = c>>7, j = c&127;
    const float* W = (m==0?Wq:(m==1?Wk:Wv)) + l*16384 + j;
    const float* nb = (m==0? n1b : nkb) + l*128;
    const float* bs = (m==0?bq:(m==1?bk:bv)) + l*128 + j;
    float a = *bs;
    for (int e=0;e<128;++e) a += nb[e]*W[e*128];
    float* dst = (m==0?bqp:(m==1?bkp:bvp));
    dst[l*128+j] = a;
  } else {
    int f = c-384;
    float a = b1[l*512+f];
    const float* W = W1 + l*65536 + f;
    const float* nb = n2b + l*128;
    for (int e=0;e<128;++e) a += nb[e]*W[e*512];
    b1F[l*512+f] = a;
  }
}

// ================= prep: weight transposes/scales (elementwise) =================
__global__ void prep_W(const float* Wq,const float* n1g,const float* Wk,const float* nkg,
                       const float* Wv,const float* Wo,const float* W1,const float* n2g,
                       const float* W2,const float* egoW,const float* outW,
                       ushort* WqB, ushort* WkB, ushort* WvB, ushort* WoB,
                       ushort* W1B, ushort* W2B, ushort* egoB, ushort* outB){
  int gid = blockIdx.x*256 + threadIdx.x;
  if (gid < 49152){
    int l=gid>>14, r=gid&16383, n=r>>7, k=r&127;
    WqB[gid] = f2bf(n1g[l*128+k]*Wq[l*16384 + k*128 + n]);
  } else if (gid < 98304){
    int q=gid-49152; int l=q>>14, r=q&16383, h=r>>11, d=(r>>4)&127, j=r&15;
    WkB[q] = f2bf(0.25f*nkg[l*128+d]*Wk[l*16384 + d*128 + h*16 + j]);
  } else if (gid < 147456){
    int q=gid-98304; int l=q>>14, r=q&16383, h=r>>11, j=(r>>7)&15, d=r&127;
    WvB[q] = f2bf(nkg[l*128+d]*Wv[l*16384 + d*128 + h*16 + j]);
  } else if (gid < 196608){
    int q=gid-147456; int l=q>>14, r=q&16383, e=r>>7, jo=r&127;
    WoB[q] = f2bf(Wo[l*16384 + jo*128 + e]);
  } else if (gid < 393216){
    int q=gid-196608; int l=q/65536, r=q%65536, f=r>>7, e=r&127;
    W1B[q] = f2bf(n2g[l*128+e]*W1[l*65536 + e*512 + f]);
  } else if (gid < 589824){
    int q=gid-393216; int l=q/65536, r=q%65536, e=r>>9, f=r&511;
    W2B[q] = f2bf(W2[l*65536 + f*128 + e]);
  } else if (gid < 606208){
    int q=gid-589824; int n=q>>7, k=q&127;
    egoB[q] = f2bf(egoW[k*128 + n]);
  } else if (gid < 622592){
    int q=gid-606208; int n=q>>7, k=q&127;
    outB[q] = f2bf(outW[k*128 + n]);
  }
}

// ================= prep: relative features + validity masks =================
__global__ void prep_rel(const float* epos, const float* evel, const float* npos, const float* nvel,
                         const int* mask, float* rel, u64* msk){
  int b = blockIdx.x*4 + (threadIdx.x>>6), n = threadIdx.x&63;
  float2 pn = ((const float2*)npos)[b*N_+n];
  float2 vn = ((const float2*)nvel)[b*N_+n];
  float2 pe = ((const float2*)epos)[b];
  float2 ve = ((const float2*)evel)[b];
  float rx=pn.x-pe.x, ry=pn.y-pe.y, rvx=vn.x-ve.x, rvy=vn.y-ve.y;
  float nrm = sqrtf(rx*rx+ry*ry);
  float dist = fmaxf(nrm,1e-6f), bear = atan2f(ry+1e-8f, rx+1e-8f);
  bool vld = (mask[b*N_+n]!=0) && (nrm<3.0f);
  u64 bal = __ballot(vld);
  if (bal==0ULL) bal = 1ULL;   // all-invalid fixup
  if (n==0) msk[b] = bal;
  float* rl = rel + ((size_t)b*N_ + n)*6;
  rl[0]=rx; rl[1]=ry; rl[2]=rvx; rl[3]=rvy; rl[4]=dist; rl[5]=bear;
}

// ================= main fused kernel =================
__global__ __launch_bounds__(256,2) void st_main(P p){
  __shared__ __align__(16) char smem[LDS_SZ];
  const int tid = threadIdx.x;
  const int w = tid>>6, l64 = tid&63;
  const int cc = l64&15, qq = l64>>4;
  const int b5 = tid>>5, sg = tid&31;
  const int bB = blockIdx.x*8;

  // stage np params (fp32 — precision-critical, R6 post-mortem) + masks
  for (int i=tid;i<768;i+=256) ((float*)(smem+OFF_NPW))[i] = p.npW[i];
  if (tid<128){
    ((float*)(smem+OFF_NPP))[tid]     = p.npb[tid];
    ((float*)(smem+OFF_NPP))[128+tid] = p.npg[tid];
    ((float*)(smem+OFF_NPP))[256+tid] = p.npbb[tid];
  }
  if (tid<8) ((u64*)(smem+OFF_MSK))[tid] = p.msk[bB+tid];
  // ego input -> XH
  {
    float4 v = *(const float4*)(p.ego + (size_t)(bB+b5)*128 + sg*4);
    uint2 o; o.x=pk2(v.x,v.y); o.y=pk2(v.z,v.w);
    *(uint2*)(smem+OFF_XH + b5*XHSTR + sg*8) = o;
  }
  __syncthreads();
  // ego GEMM -> X
  {
    FragU aF[4];
    #pragma unroll
    for (int kt=0;kt<4;++kt) aF[kt].u = *(const uint4*)(smem+OFF_XH + (cc&7)*XHSTR + kt*64 + qq*16);
    #pragma unroll
    for (int i=0;i<2;++i){
      int nt = w*2+i;
      f32x4 acc = {0.f,0.f,0.f,0.f};
      #pragma unroll
      for (int kt=0;kt<4;++kt){
        FragU bF; bF.u = *(const uint4*)(p.egoB + (nt*16+cc)*128 + kt*32 + qq*8);
        acc = __builtin_amdgcn_mfma_f32_16x16x32_bf16(aF[kt].h, bF.h, acc, 0,0,0);
      }
      if (qq<2){
        int col = nt*16+cc; float bv = p.ego_b[col];
        #pragma unroll
        for (int r=0;r<4;++r) *(float*)(smem+OFF_X+(qq*4+r)*XSTR+col*4) = acc[r]+bv;
      }
    }
  }
  __syncthreads();
  // ego LN affine (half-wave per batch)
  {
    float* xr = (float*)(smem + OFF_X + b5*XSTR + sg*16);
    float4 v = *(float4*)xr;
    float s1 = v.x+v.y+v.z+v.w, s2 = v.x*v.x+v.y*v.y+v.z*v.z+v.w*v.w;
    for (int o=1;o<32;o<<=1){ s1 += __shfl_xor(s1,o); s2 += __shfl_xor(s2,o); }
    float m = s1*0.0078125f, rs = rsqrtf(s2*0.0078125f - m*m + 1e-5f);
    int c0 = sg*4;
    v.x=(v.x-m)*rs*p.ego_g[c0+0]+p.ego_bb[c0+0];
    v.y=(v.y-m)*rs*p.ego_g[c0+1]+p.ego_bb[c0+1];
    v.z=(v.z-m)*rs*p.ego_g[c0+2]+p.ego_bb[c0+2];
    v.w=(v.w-m)*rs*p.ego_g[c0+3]+p.ego_bb[c0+3];
    *(float4*)xr = v;
  }
  __syncthreads();

  for (int li=0; li<L_; ++li){
    // ---- LN(x) -> XH (plain normalize; n1 folded into WqB/bqp) ----
    {
      const float* xr = (const float*)(smem + OFF_X + b5*XSTR + sg*16);
      float4 v = *(const float4*)xr;
      float s1 = v.x+v.y+v.z+v.w, s2 = v.x*v.x+v.y*v.y+v.z*v.z+v.w*v.w;
      for (int o=1;o<32;o<<=1){ s1 += __shfl_xor(s1,o); s2 += __shfl_xor(s2,o); }
      float m = s1*0.0078125f, rs = rsqrtf(s2*0.0078125f - m*m + 1e-5f);
      uint2 o2; o2.x = pk2((v.x-m)*rs,(v.y-m)*rs); o2.y = pk2((v.z-m)*rs,(v.w-m)*rs);
      *(uint2*)(smem + OFF_XH + b5*XHSTR + sg*8) = o2;
    }
    __syncthreads();
    // ---- Q' GEMM (M=8,N=128,K=128) -> Q bf16 ----
    {
      const ushort* W = p.WqB + li*16384;
      FragU aF[4];
      #pragma unroll
      for (int kt=0;kt<4;++kt) aF[kt].u = *(const uint4*)(smem+OFF_XH + (cc&7)*XHSTR + kt*64 + qq*16);
      #pragma unroll
      for (int i=0;i<2;++i){
        int nt = w*2+i;
        f32x4 acc = {0.f,0.f,0.f,0.f};
        #pragma unroll
        for (int kt=0;kt<4;++kt){
          FragU bF; bF.u = *(const uint4*)(W + (nt*16+cc)*128 + kt*32 + qq*8);
          acc = __builtin_amdgcn_mfma_f32_16x16x32_bf16(aF[kt].h, bF.h, acc, 0,0,0);
        }
        if (qq<2){
          int col = nt*16+cc; float bv = p.bqp[li*128+col];
          #pragma unroll
          for (int r=0;r<4;++r) *(ushort*)(smem+OFF_Q + (qq*4+r)*XHSTR + col*2) = f2bf(acc[r]+bv);
        }
      }
    }
    __syncthreads();
    // ---- qb (VALU) + qk per-head GEMMs (K=32 zero-padded) ----
    {
      int b_ = tid>>5, h = (tid>>2)&7, jq = tid&3;
      const ushort* Qr = (const ushort*)(smem+OFF_Q) + b_*136;
      float a = 0.f;
      #pragma unroll
      for (int j2=0;j2<4;++j2){
        int j = h*16 + jq*4 + j2;
        a += bf2f(Qr[j]) * p.bkp[li*128 + j];
      }
      a += __shfl_xor(a,1); a += __shfl_xor(a,2);
      if (jq==0) *(float*)(smem+OFF_QB + (b_*8+h)*4) = 0.25f*a;
    }
    {
      const ushort* W = p.WkB + li*16384;
      #pragma unroll
      for (int i=0;i<2;++i){
        int h = w*2+i;
        FragU aQ;
        if (qq<2) aQ.u = *(const uint4*)(smem+OFF_Q + (cc&7)*XHSTR + (h*16+qq*8)*2);
        else      aQ.u = make_uint4(0u,0u,0u,0u);
        #pragma unroll
        for (int nt=0;nt<8;++nt){
          f32x4 acc = {0.f,0.f,0.f,0.f};
          FragU bF; bF.u = *(const uint4*)(W + (h*128 + nt*16+cc)*16 + (qq&1)*8);
          acc = __builtin_amdgcn_mfma_f32_16x16x32_bf16(aQ.h, bF.h, acc, 0,0,0);
          if (qq<2){
            int col = nt*16+cc;
            #pragma unroll
            for (int r=0;r<4;++r)
              *(ushort*)(smem+OFF_QKA + (qq*4+r)*2176 + h*XHSTR + col*2) = f2bf(acc[r]);
          }
        }
      }
    }
    __syncthreads();

    // ---- attention rounds (R5-proven tail: ATT broadcast + VALU-U) ----
    for (int bl=0; bl<8; ++bl){
      // (a) recompute nbhat -> SL (n-major only)
      {
        const int n = w*16 + (l64>>2), jq = l64&3;
        const float* rl = p.rel + ((size_t)(bB+bl)*N_ + n)*6;
        float rx=rl[0], ry=rl[1], rvx=rl[2], rvy=rl[3], dist=rl[4], bear=rl[5];
        const float* W0 = (const float*)(smem + OFF_NPW);
        const float* PP = (const float*)(smem + OFF_NPP);
        float z[32]; float sa=0.f, sb=0.f;
        #pragma unroll
        for (int jj=0;jj<32;++jj){
          int j = jq*32+jj;
          float v = PP[j] + rx*W0[j] + ry*W0[128+j] + rvx*W0[256+j]
                          + rvy*W0[384+j] + dist*W0[512+j] + bear*W0[640+j];
          z[jj]=v; sa+=v; sb+=v*v;
        }
        sa += __shfl_xor(sa,1); sb += __shfl_xor(sb,1);
        sa += __shfl_xor(sa,2); sb += __shfl_xor(sb,2);
        float m1 = sa*0.0078125f, r1 = rsqrtf(sb*0.0078125f - m1*m1 + 1e-5f);
        float ta=0.f, tb=0.f;
        #pragma unroll
        for (int jj=0;jj<32;++jj){
          int j = jq*32+jj;
          float a = (z[jj]-m1)*r1*PP[128+j] + PP[256+j];
          a = fmaxf(a,0.f);
          z[jj]=a; ta+=a; tb+=a*a;
        }
        ta += __shfl_xor(ta,1); tb += __shfl_xor(tb,1);
        ta += __shfl_xor(ta,2); tb += __shfl_xor(tb,2);
        float m2 = ta*0.0078125f, r2 = rsqrtf(tb*0.0078125f - m2*m2 + 1e-5f);
        uint* dst = (uint*)(smem + OFF_SL + n*SLSTR + jq*64);
        #pragma unroll
        for (int q=0;q<16;++q) dst[q] = pk2((z[2*q]-m2)*r2, (z[2*q+1]-m2)*r2);
      }
      __syncthreads();
      // (b) scores MFMA (redundant on 4 waves) + softmax; wave 0 broadcasts attn
      {
        FragU bq4[4];
        #pragma unroll
        for (int kt=0;kt<4;++kt) bq4[kt].u = *(const uint4*)(smem + OFF_QKA + bl*2176 + (cc&7)*XHSTR + kt*64 + qq*16);
        f32x4 c[4];
        #pragma unroll
        for (int mt=0;mt<4;++mt){
          f32x4 acc = {0.f,0.f,0.f,0.f};
          #pragma unroll
          for (int kt=0;kt<4;++kt){
            uint2 lo = *(const uint2*)(smem + OFF_SL + (mt*16+cc)*SLSTR + kt*64 + qq*16);
            uint2 hi = *(const uint2*)(smem + OFF_SL + (mt*16+cc)*SLSTR + kt*64 + qq*16 + 8);
            FragU a; a.u = make_uint4(lo.x, lo.y, hi.x, hi.y);
            acc = __builtin_amdgcn_mfma_f32_16x16x32_bf16(a.h, bq4[kt].h, acc, 0,0,0);
          }
          c[mt]=acc;
        }
        float qbv = *(const float*)(smem + OFF_QB + (bl*8+(cc&7))*4);
        u64 vm = ((const u64*)(smem+OFF_MSK))[bl];
        float sc[16];
        #pragma unroll
        for (int mt=0;mt<4;++mt)
          #pragma unroll
          for (int r=0;r<4;++r){
            int n = mt*16 + qq*4 + r;
            sc[mt*4+r] = ((vm>>n)&1ULL) ? (c[mt][r]+qbv) : -1e9f;
          }
        float mx = -3e38f;
        #pragma unroll
        for (int k=0;k<16;++k) mx = fmaxf(mx, sc[k]);
        mx = fmaxf(mx,__shfl_xor(mx,16)); mx = fmaxf(mx,__shfl_xor(mx,32));
        float ex[16], se = 0.f;
        #pragma unroll
        for (int k=0;k<16;++k){ ex[k]=__expf(sc[k]-mx); se+=ex[k]; }
        se += __shfl_xor(se,16); se += __shfl_xor(se,32);
        float inv = 1.f/se;
        if (w==0 && cc<8){
          float* A = (float*)(smem+OFF_ATT);
          #pragma unroll
          for (int mt=0;mt<4;++mt)
            #pragma unroll
            for (int r=0;r<4;++r) A[cc*64 + (mt*16+qq*4+r)] = ex[mt*4+r]*inv;
        }
      }
      __syncthreads();
      // (c) U via VALU (R5 pattern): lane = d-pair (l64), wave = h-pair
      {
        const int h0 = 2*w, h1 = 2*w+1;
        const float* att = (const float*)(smem + OFF_ATT);
        float u00=0.f,u01=0.f,u10=0.f,u11=0.f;
        #pragma unroll 8
        for (int n=0;n<N_;++n){
          uint pr = *(const uint*)(smem + OFF_SL + n*SLSTR + l64*4);
          float flo = bflo(pr), fhi = bfhi(pr);
          float a0 = att[h0*64+n], a1 = att[h1*64+n];
          u00 += a0*flo; u01 += a0*fhi; u10 += a1*flo; u11 += a1*fhi;
        }
        uint* ua = (uint*)(smem + OFF_UA + bl*UASTR);
        ua[h0*64 + l64] = pk2(u00,u01);
        ua[h1*64 + l64] = pk2(u10,u11);
      }
      __syncthreads();
    } // rounds

    // ---- ctx: per-head U @ WvB (+bvp) -> CX ----
    {
      const ushort* W = p.WvB + li*16384;
      #pragma unroll
      for (int i=0;i<2;++i){
        int h = w*2+i;
        f32x4 acc = {0.f,0.f,0.f,0.f};
        #pragma unroll
        for (int kt=0;kt<4;++kt){
          FragU a,bF;
          a.u = *(const uint4*)(smem + OFF_UA + (cc&7)*UASTR + (h*128 + kt*32 + qq*8)*2);
          bF.u = *(const uint4*)(W + h*2048 + cc*128 + kt*32 + qq*8);
          acc = __builtin_amdgcn_mfma_f32_16x16x32_bf16(a.h, bF.h, acc, 0,0,0);
        }
        if (qq<2){
          int col = h*16+cc;
          float bv = p.bvp[li*128+col];
          #pragma unroll
          for (int r=0;r<4;++r)
            *(ushort*)(smem+OFF_CX + (qq*4+r)*XHSTR + col*2) = f2bf(acc[r]+bv);
        }
      }
    }
    __syncthreads();
    // ---- x += CX @ WoB + bo ----
    {
      const ushort* W = p.WoB + li*16384;
      FragU aF[4];
      #pragma unroll
      for (int kt=0;kt<4;++kt) aF[kt].u = *(const uint4*)(smem+OFF_CX + (cc&7)*XHSTR + kt*64 + qq*16);
      #pragma unroll
      for (int i=0;i<2;++i){
        int nt = w*2+i;
        f32x4 acc = {0.f,0.f,0.f,0.f};
        #pragma unroll
        for (int kt=0;kt<4;++kt){
          FragU bF; bF.u = *(const uint4*)(W + (nt*16+cc)*128 + kt*32 + qq*8);
          acc = __builtin_amdgcn_mfma_f32_16x16x32_bf16(aF[kt].h, bF.h, acc, 0,0,0);
        }
        if (qq<2){
          int col = nt*16+cc; float bv = p.bo[li*128+col];
          #pragma unroll
          for (int r=0;r<4;++r){
            float* xp = (float*)(smem + OFF_X + (qq*4+r)*XSTR + col*4);
            *xp += acc[r]+bv;
          }
        }
      }
    }
    __syncthreads();
    // ---- FFN: LN(x) -> XH (n2 folded into W1B/b1F) ----
    {
      const float* xr = (const float*)(smem + OFF_X + b5*XSTR + sg*16);
      float4 v = *(const float4*)xr;
      float s1 = v.x+v.y+v.z+v.w, s2 = v.x*v.x+v.y*v.y+v.z*v.z+v.w*v.w;
      for (int o=1;o<32;o<<=1){ s1 += __shfl_xor(s1,o); s2 += __shfl_xor(s2,o); }
      float m = s1*0.0078125f, rs = rsqrtf(s2*0.0078125f - m*m + 1e-5f);
      uint2 o2; o2.x = pk2((v.x-m)*rs,(v.y-m)*rs); o2.y = pk2((v.z-m)*rs,(v.w-m)*rs);
      *(uint2*)(smem + OFF_XH + b5*XHSTR + sg*8) = o2;
    }
    __syncthreads();
    // W1 GEMM + gelu -> H1 (aliases QKA)
    {
      const ushort* W = p.W1B + (size_t)li*65536;
      const float* b1l = p.b1F + li*512;
      FragU aF[4];
      #pragma unroll
      for (int kt=0;kt<4;++kt) aF[kt].u = *(const uint4*)(smem + OFF_XH + (cc&7)*XHSTR + kt*64 + qq*16);
      #pragma unroll
      for (int it=0;it<8;++it){
        int nt = w*8+it;
        f32x4 acc = {0.f,0.f,0.f,0.f};
        #pragma unroll
        for (int kt=0;kt<4;++kt){
          FragU bF; bF.u = *(const uint4*)(W + (nt*16+cc)*128 + kt*32 + qq*8);
          acc = __builtin_amdgcn_mfma_f32_16x16x32_bf16(aF[kt].h, bF.h, acc, 0,0,0);
        }
        if (qq<2){
          int col = nt*16+cc; float bv = b1l[col];
          #pragma unroll
          for (int r=0;r<4;++r){
            float v = acc[r]+bv;
            v = 0.5f*v*(1.f+erff(v*0.70710678118654752f));
            *(ushort*)(smem + OFF_QKA + (qq*4+r)*1040 + col*2) = f2bf(v);
          }
        }
      }
    }
    __syncthreads();
    // W2 GEMM -> X += (K=512)
    {
      const ushort* W = p.W2B + (size_t)li*65536;
      #pragma unroll
      for (int i=0;i<2;++i){
        int nt = w*2+i;
        f32x4 acc = {0.f,0.f,0.f,0.f};
        #pragma unroll 8
        for (int kt=0;kt<16;++kt){
          FragU a,bF;
          a.u = *(const uint4*)(smem + OFF_QKA + (cc&7)*1040 + kt*64 + qq*16);
          bF.u = *(const uint4*)(W + (nt*16+cc)*512 + kt*32 + qq*8);
          acc = __builtin_amdgcn_mfma_f32_16x16x32_bf16(a.h, bF.h, acc, 0,0,0);
        }
        if (qq<2){
          int col = nt*16+cc; float bv = p.b2[li*128+col];
          #pragma unroll
          for (int r=0;r<4;++r){
            float* xp = (float*)(smem + OFF_X + (qq*4+r)*XSTR + col*4);
            *xp += acc[r]+bv;
          }
        }
      }
    }
    __syncthreads();
  } // layers

  // ---- output: LN(x @ outB + out_b) ----
  {
    const float* xr = (const float*)(smem + OFF_X + b5*XSTR + sg*16);
    float4 v = *(const float4*)xr;
    uint2 o2; o2.x = pk2(v.x,v.y); o2.y = pk2(v.z,v.w);
    *(uint2*)(smem + OFF_XH + b5*XHSTR + sg*8) = o2;
  }
  __syncthreads();
  {
    FragU aF[4];
    #pragma unroll
    for (int kt=0;kt<4;++kt) aF[kt].u = *(const uint4*)(smem + OFF_XH + (cc&7)*XHSTR + kt*64 + qq*16);
    #pragma unroll
    for (int i=0;i<2;++i){
      int nt = w*2+i;
      f32x4 acc = {0.f,0.f,0.f,0.f};
      #pragma unroll
      for (int kt=0;kt<4;++kt){
        FragU bF; bF.u = *(const uint4*)(p.outB + (nt*16+cc)*128 + kt*32 + qq*8);
        acc = __builtin_amdgcn_mfma_f32_16x16x32_bf16(aF[kt].h, bF.h, acc, 0,0,0);
      }
      if (qq<2){
        int col = nt*16+cc; float bv = p.out_b[col];
        #pragma unroll
        for (int r=0;r<4;++r) *(float*)(smem + OFF_X + (qq*4+r)*XSTR + col*4) = acc[r]+bv;
      }
    }
  }
  __syncthreads();
  {
    const float* xr = (const float*)(smem + OFF_X + b5*XSTR + sg*16);
    float4 v = *(const float4*)xr;
    float s1 = v.x+v.y+v.z+v.w, s2 = v.x*v.x+v.y*v.y+v.z*v.z+v.w*v.w;
    for (int o=1;o<32;o<<=1){ s1 += __shfl_xor(s1,o); s2 += __shfl_xor(s2,o); }
    float m = s1*0.0078125f, rs = rsqrtf(s2*0.0078125f - m*m + 1e-5f);
    int c0 = sg*4;
    float4 o4;
    o4.x = (v.x-m)*rs*p.out_g[c0+0]+p.out_bb[c0+0];
    o4.y = (v.y-m)*rs*p.out_g[c0+1]+p.out_bb[c0+1];
    o4.z = (v.z-m)*rs*p.out_g[c0+2]+p.out_bb[c0+2];
    o4.w = (v.w-m)*rs*p.out_g[c0+3]+p.out_bb[c0+3];
    *(float4*)(p.outp + (size_t)(bB+b5)*128 + sg*4) = o4;
  }
}

// ================= host =================
extern "C" void kernel_launch(void* const* d_in, const int* in_sizes, int n_in,
                              void* d_out, int out_size, void* d_ws, size_t ws_size,
                              hipStream_t stream){
  (void)in_sizes; (void)n_in; (void)out_size; (void)ws_size;
  char* ws = (char*)d_ws;
  ushort* WqB  = (ushort*)(ws + 0);         // 98304
  ushort* WkB  = (ushort*)(ws + 98304);     // 98304
  ushort* WvB  = (ushort*)(ws + 196608);    // 98304
  ushort* WoB  = (ushort*)(ws + 294912);    // 98304
  ushort* W1B  = (ushort*)(ws + 393216);    // 393216
  ushort* W2B  = (ushort*)(ws + 786432);    // 393216
  ushort* egoB = (ushort*)(ws + 1179648);   // 32768
  ushort* outB = (ushort*)(ws + 1212416);   // 32768
  float*  bqp  = (float*) (ws + 1245184);   // 1536
  float*  bkp  = (float*) (ws + 1246720);   // 1536
  float*  bvp  = (float*) (ws + 1248256);   // 1536
  float*  b1F  = (float*) (ws + 1249792);   // 6144
  float*  rel  = (float*) (ws + 1255936);   // 12582912
  u64*    msk  = (u64*)   (ws + 13838848);  // 65536 -> ends 13904384 (~13.9 MB)

  prep_bias<<<11,256,0,stream>>>((const float*)d_in[20],(const float*)d_in[21],(const float*)d_in[15],
                                 (const float*)d_in[22],(const float*)d_in[23],(const float*)d_in[17],
                                 (const float*)d_in[24],(const float*)d_in[25],
                                 (const float*)d_in[28],(const float*)d_in[29],(const float*)d_in[19],
                                 bqp,bkp,bvp,b1F);
  prep_W<<<2432,256,0,stream>>>((const float*)d_in[20],(const float*)d_in[14],
                                (const float*)d_in[22],(const float*)d_in[16],
                                (const float*)d_in[24],(const float*)d_in[26],
                                (const float*)d_in[28],(const float*)d_in[18],
                                (const float*)d_in[30],(const float*)d_in[10],(const float*)d_in[32],
                                WqB,WkB,WvB,WoB,W1B,W2B,egoB,outB);
  prep_rel<<<B_/4,256,0,stream>>>((const float*)d_in[1],(const float*)d_in[2],
                                  (const float*)d_in[3],(const float*)d_in[4],
                                  (const int*)d_in[5], rel, msk);
  P p;
  p.ego=(const float*)d_in[0];
  p.ego_b=(const float*)d_in[11]; p.ego_g=(const float*)d_in[12]; p.ego_bb=(const float*)d_in[13];
  p.npW=(const float*)d_in[6]; p.npb=(const float*)d_in[7]; p.npg=(const float*)d_in[8]; p.npbb=(const float*)d_in[9];
  p.bo=(const float*)d_in[27]; p.b2=(const float*)d_in[31];
  p.out_b=(const float*)d_in[33]; p.out_g=(const float*)d_in[34]; p.out_bb=(const float*)d_in[35];
  p.bqp=bqp; p.bkp=bkp; p.bvp=bvp; p.b1F=b1F;
  p.WqB=WqB; p.WkB=WkB; p.WvB=WvB; p.WoB=WoB; p.W1B=W1B; p.W2B=W2B; p.egoB=egoB; p.outB=outB;
  p.rel=rel; p.msk=msk;
  p.outp=(float*)d_out;

  st_main<<<B_/8,256,0,stream>>>(p);
}